// Round 1
// baseline (563.236 us; speedup 1.0000x reference)
//
#include <hip/hip_runtime.h>
#include <math.h>

#define N_TOK 8192
#define C_DIM 128
#define NHD   8
#define HDIM  16
#define NR    1024
#define EPSV  1e-5f
#define QK_SCALE 0.25f

__device__ __forceinline__ float gelu_f(float v) {
    return 0.5f * v * (1.0f + erff(v * 0.70710678118654752f));
}

// ---------------- transpose x (C,N) -> xt (N,C) ----------------
__global__ __launch_bounds__(256) void transpose_k(const float* __restrict__ x,
                                                   float* __restrict__ xt) {
    __shared__ float tile[32][33];
    int n0 = blockIdx.x * 32, c0 = blockIdx.y * 32;
    int tx = threadIdx.x, ty = threadIdx.y;
#pragma unroll
    for (int k = 0; k < 4; ++k)
        tile[ty + k * 8][tx] = x[(size_t)(c0 + ty + k * 8) * N_TOK + n0 + tx];
    __syncthreads();
#pragma unroll
    for (int k = 0; k < 4; ++k)
        xt[(size_t)(n0 + ty + k * 8) * C_DIM + c0 + tx] = tile[tx][ty + k * 8];
}

// ---------------- token LayerNorm over C=128, up to two gamma/beta sets ----------------
__global__ __launch_bounds__(256) void ln_token_k(const float* __restrict__ in,
                                                  const float* __restrict__ g1, const float* __restrict__ b1,
                                                  float* __restrict__ o1,
                                                  const float* __restrict__ g2, const float* __restrict__ b2,
                                                  float* __restrict__ o2) {
    int lane = threadIdx.x & 63;
    int n = blockIdx.x * 4 + (threadIdx.x >> 6);
    float v0 = in[(size_t)n * C_DIM + lane];
    float v1 = in[(size_t)n * C_DIM + 64 + lane];
    float s = v0 + v1, sq = v0 * v0 + v1 * v1;
#pragma unroll
    for (int off = 32; off >= 1; off >>= 1) {
        s += __shfl_xor(s, off);
        sq += __shfl_xor(sq, off);
    }
    float m = s * (1.0f / 128.0f);
    float var = sq * (1.0f / 128.0f) - m * m;
    float rs = rsqrtf(var + EPSV);
    float h0 = (v0 - m) * rs, h1 = (v1 - m) * rs;
    o1[(size_t)n * C_DIM + lane]      = h0 * g1[lane] + b1[lane];
    o1[(size_t)n * C_DIM + 64 + lane] = h1 * g1[lane + 64] + b1[lane + 64];
    if (o2) {
        o2[(size_t)n * C_DIM + lane]      = h0 * g2[lane] + b2[lane];
        o2[(size_t)n * C_DIM + 64 + lane] = h1 * g2[lane + 64] + b2[lane + 64];
    }
}

// ---------------- generic tiled fp32 GEMM: C = A(MxK) @ W(NxK)^T (+bias)(+gelu / +res) ----------------
// EPI: 0 = none, 1 = +bias, 2 = +bias then gelu, 3 = +bias then +res
template <int EPI>
__global__ __launch_bounds__(256) void gemm_k(const float* __restrict__ A,
                                              const float* __restrict__ W,
                                              const float* __restrict__ bias,
                                              const float* __restrict__ res,
                                              float* __restrict__ Cm,
                                              int M, int N, int K) {
    __shared__ float As[16][64];
    __shared__ float Ws[16][64];
    int t = threadIdx.x;
    int tm = t & 15, tn = t >> 4;
    int m0 = blockIdx.x * 64, n0 = blockIdx.y * 64;
    int lrow = t >> 2;
    int lk = (t & 3) * 4;
    float acc[4][4] = {};
    for (int k0 = 0; k0 < K; k0 += 16) {
        float4 av = *(const float4*)&A[(size_t)(m0 + lrow) * K + k0 + lk];
        float4 wv = *(const float4*)&W[(size_t)(n0 + lrow) * K + k0 + lk];
        __syncthreads();
        As[lk + 0][lrow] = av.x; As[lk + 1][lrow] = av.y;
        As[lk + 2][lrow] = av.z; As[lk + 3][lrow] = av.w;
        Ws[lk + 0][lrow] = wv.x; Ws[lk + 1][lrow] = wv.y;
        Ws[lk + 2][lrow] = wv.z; Ws[lk + 3][lrow] = wv.w;
        __syncthreads();
#pragma unroll
        for (int k = 0; k < 16; ++k) {
            float4 a = *(const float4*)&As[k][tm * 4];
            float4 b = *(const float4*)&Ws[k][tn * 4];
            acc[0][0] += a.x * b.x; acc[0][1] += a.x * b.y; acc[0][2] += a.x * b.z; acc[0][3] += a.x * b.w;
            acc[1][0] += a.y * b.x; acc[1][1] += a.y * b.y; acc[1][2] += a.y * b.z; acc[1][3] += a.y * b.w;
            acc[2][0] += a.z * b.x; acc[2][1] += a.z * b.y; acc[2][2] += a.z * b.z; acc[2][3] += a.z * b.w;
            acc[3][0] += a.w * b.x; acc[3][1] += a.w * b.y; acc[3][2] += a.w * b.z; acc[3][3] += a.w * b.w;
        }
    }
    float4 bv = make_float4(0.f, 0.f, 0.f, 0.f);
    if (EPI >= 1) bv = *(const float4*)&bias[n0 + tn * 4];
#pragma unroll
    for (int i = 0; i < 4; ++i) {
        int r = m0 + tm * 4 + i;
        float4 v;
        v.x = acc[i][0] + bv.x; v.y = acc[i][1] + bv.y;
        v.z = acc[i][2] + bv.z; v.w = acc[i][3] + bv.w;
        if (EPI == 2) {
            v.x = gelu_f(v.x); v.y = gelu_f(v.y); v.z = gelu_f(v.z); v.w = gelu_f(v.w);
        }
        if (EPI == 3) {
            float4 rv = *(const float4*)&res[(size_t)r * N + n0 + tn * 4];
            v.x += rv.x; v.y += rv.y; v.z += rv.z; v.w += rv.w;
        }
        *(float4*)&Cm[(size_t)r * N + n0 + tn * 4] = v;
    }
}

// ---------------- local patch attention (R=256 patches, 8 heads, 32 tokens, HD=16) ----------------
__global__ __launch_bounds__(256) void local_attn_k(const float* __restrict__ qkv,
                                                    float* __restrict__ ob) {
    __shared__ float ks[NHD][32][HDIM];
    __shared__ float vs[NHD][32][HDIM];
    int m = threadIdx.x, h = threadIdx.y, r = blockIdx.x;
    int zd = r >> 6, zh = (r >> 3) & 7, zw = r & 7;
    int pd = m >> 4, ph = (m >> 2) & 3, pw = m & 3;
    int n = (zd * 2 + pd) * 1024 + (zh * 4 + ph) * 32 + (zw * 4 + pw);
    const float* base = qkv + (size_t)n * 384 + h * HDIM;
    float q[16];
#pragma unroll
    for (int i = 0; i < 4; ++i) {
        float4 qv = *(const float4*)(base + i * 4);
        q[i * 4 + 0] = qv.x; q[i * 4 + 1] = qv.y; q[i * 4 + 2] = qv.z; q[i * 4 + 3] = qv.w;
        *(float4*)&ks[h][m][i * 4] = *(const float4*)(base + 128 + i * 4);
        *(float4*)&vs[h][m][i * 4] = *(const float4*)(base + 256 + i * 4);
    }
    __syncthreads();
    float s[32];
    float mx = -1e30f;
#pragma unroll
    for (int j = 0; j < 32; ++j) {
        float d = 0.f;
#pragma unroll
        for (int dd = 0; dd < 16; ++dd) d += q[dd] * ks[h][j][dd];
        s[j] = d * QK_SCALE;
        mx = fmaxf(mx, s[j]);
    }
    float sum = 0.f;
#pragma unroll
    for (int j = 0; j < 32; ++j) { s[j] = __expf(s[j] - mx); sum += s[j]; }
    float inv = 1.0f / sum;
    float oo[16] = {};
#pragma unroll
    for (int j = 0; j < 32; ++j) {
        float p = s[j] * inv;
#pragma unroll
        for (int dd = 0; dd < 16; ++dd) oo[dd] += p * vs[h][j][dd];
    }
    // torch-faithful quirk: o (NH,Npl,HD) -> swap(-1,-2) -> reshape (Npl, C)
#pragma unroll
    for (int dd = 0; dd < 16; ++dd) {
        int n2 = h * 4 + (dd >> 2);
        int c2 = (dd & 3) * 32 + m;
        int pd2 = n2 >> 4, ph2 = (n2 >> 2) & 3, pw2 = n2 & 3;
        int nn = (zd * 2 + pd2) * 1024 + (zh * 4 + ph2) * 32 + (zw * 4 + pw2);
        ob[(size_t)nn * C_DIM + c2] = oo[dd];
    }
}

// ---------------- gather reduced K/V conv inputs: kg/vg (Nr=1024, 1024) ----------------
__global__ __launch_bounds__(256) void gather_k(const float* __restrict__ qkv,
                                                float* __restrict__ kg, float* __restrict__ vg) {
    int idx = blockIdx.x * 256 + threadIdx.x;
    int nr = idx >> 10, qq = idx & 1023;
    int ci = qq >> 3, off = qq & 7;
    int od = off >> 2, oh = (off >> 1) & 1, ow = off & 1;
    int d2 = nr >> 8, h2 = (nr >> 4) & 15, w2 = nr & 15;
    int n = (2 * d2 + od) * 1024 + (2 * h2 + oh) * 32 + (2 * w2 + ow);
    kg[idx] = qkv[(size_t)n * 384 + 128 + ci];
    vg[idx] = qkv[(size_t)n * 384 + 256 + ci];
}

// ---------------- per-head LN over HD=16 on reduced K/V (in place) ----------------
__global__ __launch_bounds__(256) void ln_head_k(float* __restrict__ buf,
                                                 const float* __restrict__ g, const float* __restrict__ b) {
    int idx = blockIdx.x * 256 + threadIdx.x; // 8192 = 1024*8
    int nr = idx >> 3, h = idx & 7;
    float* p = buf + (size_t)nr * C_DIM + h * HDIM;
    float v[16];
    float s = 0.f;
#pragma unroll
    for (int i = 0; i < 16; ++i) { v[i] = p[i]; s += v[i]; }
    float m = s * (1.0f / 16.0f);
    float sq = 0.f;
#pragma unroll
    for (int i = 0; i < 16; ++i) { float d = v[i] - m; sq += d * d; }
    float rs = rsqrtf(sq * (1.0f / 16.0f) + EPSV);
#pragma unroll
    for (int i = 0; i < 16; ++i) p[i] = (v[i] - m) * rs * g[i] + b[i];
}

// ---------------- global attention: q (N,heads) vs kr/vr (Nr=1024), flash-style ----------------
__global__ __launch_bounds__(256) void gattn_k(const float* __restrict__ qkv,
                                               const float* __restrict__ kr, const float* __restrict__ vr,
                                               float* __restrict__ ob) {
    __shared__ float kch[64][HDIM];
    __shared__ float vch[64][HDIM];
    int h = blockIdx.y;
    int n = blockIdx.x * 256 + threadIdx.x;
    const float* qb = qkv + (size_t)n * 384 + h * HDIM;
    float q[16];
#pragma unroll
    for (int i = 0; i < 16; ++i) q[i] = qb[i];
    float mx = -1e30f, sm = 0.f;
    float o[16] = {};
    for (int c0 = 0; c0 < NR; c0 += 64) {
        __syncthreads();
        int t = threadIdx.x;
#pragma unroll
        for (int i = t; i < 512; i += 256) {
            int which = i >> 8, j = i & 255, row = j >> 2, d4 = j & 3;
            const float* src = which ? vr : kr;
            float4 val = *(const float4*)(src + (size_t)(c0 + row) * C_DIM + h * HDIM + d4 * 4);
            float* dst = which ? &vch[row][d4 * 4] : &kch[row][d4 * 4];
            *(float4*)dst = val;
        }
        __syncthreads();
        float sv[64];
#pragma unroll
        for (int j = 0; j < 64; ++j) {
            float d = 0.f;
#pragma unroll
            for (int dd = 0; dd < 16; ++dd) d += q[dd] * kch[j][dd];
            sv[j] = d * QK_SCALE;
        }
        float cm = -1e30f;
#pragma unroll
        for (int j = 0; j < 64; ++j) cm = fmaxf(cm, sv[j]);
        float nmx = fmaxf(mx, cm);
        float corr = __expf(mx - nmx);
        sm *= corr;
#pragma unroll
        for (int dd = 0; dd < 16; ++dd) o[dd] *= corr;
#pragma unroll
        for (int j = 0; j < 64; ++j) {
            float p = __expf(sv[j] - nmx);
            sm += p;
#pragma unroll
            for (int dd = 0; dd < 16; ++dd) o[dd] += p * vch[j][dd];
        }
        mx = nmx;
    }
    float inv = 1.0f / sm;
    float* dst = ob + (size_t)n * C_DIM + h * HDIM;
#pragma unroll
    for (int i = 0; i < 4; ++i) {
        float4 v = make_float4(o[i * 4] * inv, o[i * 4 + 1] * inv, o[i * 4 + 2] * inv, o[i * 4 + 3] * inv);
        *(float4*)(dst + i * 4) = v;
    }
}

// ---------------- final gate: out(C,N) = x * sigmoid(loc + glo) ----------------
__global__ __launch_bounds__(256) void gate_k(const float* __restrict__ x,
                                              const float* __restrict__ lf, const float* __restrict__ gf,
                                              float* __restrict__ out) {
    __shared__ float tile[32][33];
    int n0 = blockIdx.x * 32, c0 = blockIdx.y * 32;
    int tx = threadIdx.x, ty = threadIdx.y;
#pragma unroll
    for (int k = 0; k < 4; ++k) {
        int n = n0 + ty + k * 8, c = c0 + tx;
        tile[ty + k * 8][tx] = lf[(size_t)n * C_DIM + c] + gf[(size_t)n * C_DIM + c];
    }
    __syncthreads();
#pragma unroll
    for (int k = 0; k < 4; ++k) {
        int c = c0 + ty + k * 8, n = n0 + tx;
        float z = tile[tx][ty + k * 8];
        float sg = 1.0f / (1.0f + __expf(-z));
        out[(size_t)c * N_TOK + n] = x[(size_t)c * N_TOK + n] * sg;
    }
}

extern "C" void kernel_launch(void* const* d_in, const int* in_sizes, int n_in,
                              void* d_out, int out_size, void* d_ws, size_t ws_size,
                              hipStream_t stream) {
    const float* x        = (const float*)d_in[0];
    const float* l_n1_g   = (const float*)d_in[1];
    const float* l_n1_b   = (const float*)d_in[2];
    const float* l_qkv_w  = (const float*)d_in[3];
    const float* l_proj_w = (const float*)d_in[4];
    const float* l_proj_b = (const float*)d_in[5];
    const float* l_n2_g   = (const float*)d_in[6];
    const float* l_n2_b   = (const float*)d_in[7];
    const float* l_fc1_w  = (const float*)d_in[8];
    const float* l_fc1_b  = (const float*)d_in[9];
    const float* l_fc2_w  = (const float*)d_in[10];
    const float* l_fc2_b  = (const float*)d_in[11];
    const float* g_n1_g   = (const float*)d_in[12];
    const float* g_n1_b   = (const float*)d_in[13];
    const float* g_qkv_w  = (const float*)d_in[14];
    const float* g_proj_w = (const float*)d_in[15];
    const float* g_proj_b = (const float*)d_in[16];
    const float* g_n2_g   = (const float*)d_in[17];
    const float* g_n2_b   = (const float*)d_in[18];
    const float* g_fc1_w  = (const float*)d_in[19];
    const float* g_fc1_b  = (const float*)d_in[20];
    const float* g_fc2_w  = (const float*)d_in[21];
    const float* g_fc2_b  = (const float*)d_in[22];
    const float* g_ke_w   = (const float*)d_in[23];
    const float* g_ve_w   = (const float*)d_in[24];
    const float* g_nk_g   = (const float*)d_in[25];
    const float* g_nk_b   = (const float*)d_in[26];
    const float* g_nv_g   = (const float*)d_in[27];
    const float* g_nv_b   = (const float*)d_in[28];
    float* out = (float*)d_out;

    float* ws = (float*)d_ws;
    float* xt     = ws;               // 1048576
    float* locfin = ws + 1048576;     // 1048576
    float* glofin = ws + 2097152;     // 1048576
    float* yA     = ws + 3145728;     // 1048576
    float* qkvb   = ws + 4194304;     // 3145728
    float* obuf   = ws + 7340032;     // 1048576
    float* t1     = ws + 8388608;     // 1048576
    float* t2     = ws + 9437184;     // 1048576
    float* h1     = ws + 10485760;    // 4194304
    float* kg     = ws + 14680064;    // 1048576
    float* vg     = ws + 15728640;    // 1048576
    float* krb    = ws + 16777216;    // 131072
    float* vrb    = ws + 16908288;    // 131072
    float* yG     = ws + 17039360;    // 1048576 (second LN output, kept separate)

    // ---- shared preamble ----
    transpose_k<<<dim3(256, 4), dim3(32, 8), 0, stream>>>(x, xt);
    ln_token_k<<<2048, 256, 0, stream>>>(xt, l_n1_g, l_n1_b, yA, g_n1_g, g_n1_b, yG);

    // ---- local branch ----
    gemm_k<0><<<dim3(128, 6), 256, 0, stream>>>(yA, l_qkv_w, nullptr, nullptr, qkvb, N_TOK, 384, 128);
    local_attn_k<<<256, dim3(32, 8), 0, stream>>>(qkvb, obuf);
    gemm_k<3><<<dim3(128, 2), 256, 0, stream>>>(obuf, l_proj_w, l_proj_b, xt, t1, N_TOK, 128, 128);
    ln_token_k<<<2048, 256, 0, stream>>>(t1, l_n2_g, l_n2_b, t2, nullptr, nullptr, nullptr);
    gemm_k<2><<<dim3(128, 8), 256, 0, stream>>>(t2, l_fc1_w, l_fc1_b, nullptr, h1, N_TOK, 512, 128);
    gemm_k<3><<<dim3(128, 2), 256, 0, stream>>>(h1, l_fc2_w, l_fc2_b, t1, locfin, N_TOK, 128, 512);

    // ---- global branch ----
    gemm_k<0><<<dim3(128, 6), 256, 0, stream>>>(yG, g_qkv_w, nullptr, nullptr, qkvb, N_TOK, 384, 128);
    gather_k<<<4096, 256, 0, stream>>>(qkvb, kg, vg);
    gemm_k<0><<<dim3(16, 2), 256, 0, stream>>>(kg, g_ke_w, nullptr, nullptr, krb, NR, 128, 1024);
    gemm_k<0><<<dim3(16, 2), 256, 0, stream>>>(vg, g_ve_w, nullptr, nullptr, vrb, NR, 128, 1024);
    ln_head_k<<<32, 256, 0, stream>>>(krb, g_nk_g, g_nk_b);
    ln_head_k<<<32, 256, 0, stream>>>(vrb, g_nv_g, g_nv_b);
    gattn_k<<<dim3(32, 8), 256, 0, stream>>>(qkvb, krb, vrb, obuf);
    gemm_k<3><<<dim3(128, 2), 256, 0, stream>>>(obuf, g_proj_w, g_proj_b, xt, t1, N_TOK, 128, 128);
    ln_token_k<<<2048, 256, 0, stream>>>(t1, g_n2_g, g_n2_b, t2, nullptr, nullptr, nullptr);
    gemm_k<2><<<dim3(128, 8), 256, 0, stream>>>(t2, g_fc1_w, g_fc1_b, nullptr, h1, N_TOK, 512, 128);
    gemm_k<3><<<dim3(128, 2), 256, 0, stream>>>(h1, g_fc2_w, g_fc2_b, t1, glofin, N_TOK, 128, 512);

    // ---- gate ----
    gate_k<<<dim3(256, 4), dim3(32, 8), 0, stream>>>(x, locfin, glofin, out);
}

// Round 2
// 366.012 us; speedup vs baseline: 1.5388x; 1.5388x over previous
//
#include <hip/hip_runtime.h>
#include <math.h>

#define N_TOK 8192
#define C_DIM 128
#define NHD   8
#define HDIM  16
#define NR    1024
#define EPSV  1e-5f
#define QK_SCALE 0.25f

__device__ __forceinline__ float gelu_f(float v) {
    return 0.5f * v * (1.0f + erff(v * 0.70710678118654752f));
}

// ---------------- transpose x (C,N) -> xt (N,C) ----------------
__global__ __launch_bounds__(256) void transpose_k(const float* __restrict__ x,
                                                   float* __restrict__ xt) {
    __shared__ float tile[32][33];
    int n0 = blockIdx.x * 32, c0 = blockIdx.y * 32;
    int tx = threadIdx.x, ty = threadIdx.y;
#pragma unroll
    for (int k = 0; k < 4; ++k)
        tile[ty + k * 8][tx] = x[(size_t)(c0 + ty + k * 8) * N_TOK + n0 + tx];
    __syncthreads();
#pragma unroll
    for (int k = 0; k < 4; ++k)
        xt[(size_t)(n0 + ty + k * 8) * C_DIM + c0 + tx] = tile[tx][ty + k * 8];
}

// ---------------- token LayerNorm over C=128, up to two gamma/beta sets ----------------
__global__ __launch_bounds__(256) void ln_token_k(const float* __restrict__ in,
                                                  const float* __restrict__ g1, const float* __restrict__ b1,
                                                  float* __restrict__ o1,
                                                  const float* __restrict__ g2, const float* __restrict__ b2,
                                                  float* __restrict__ o2) {
    int lane = threadIdx.x & 63;
    int n = blockIdx.x * 4 + (threadIdx.x >> 6);
    float v0 = in[(size_t)n * C_DIM + lane];
    float v1 = in[(size_t)n * C_DIM + 64 + lane];
    float s = v0 + v1, sq = v0 * v0 + v1 * v1;
#pragma unroll
    for (int off = 32; off >= 1; off >>= 1) {
        s += __shfl_xor(s, off);
        sq += __shfl_xor(sq, off);
    }
    float m = s * (1.0f / 128.0f);
    float var = sq * (1.0f / 128.0f) - m * m;
    float rs = rsqrtf(var + EPSV);
    float h0 = (v0 - m) * rs, h1 = (v1 - m) * rs;
    o1[(size_t)n * C_DIM + lane]      = h0 * g1[lane] + b1[lane];
    o1[(size_t)n * C_DIM + 64 + lane] = h1 * g1[lane + 64] + b1[lane + 64];
    if (o2) {
        o2[(size_t)n * C_DIM + lane]      = h0 * g2[lane] + b2[lane];
        o2[(size_t)n * C_DIM + 64 + lane] = h1 * g2[lane + 64] + b2[lane + 64];
    }
}

// ---------------- generic tiled fp32 GEMM: C = A(MxK) @ W(NxK)^T (+bias)(+gelu / +res) ----------------
// EPI: 0 = none, 1 = +bias, 2 = +bias then gelu, 3 = +bias then +res
template <int EPI>
__global__ __launch_bounds__(256) void gemm_k(const float* __restrict__ A,
                                              const float* __restrict__ W,
                                              const float* __restrict__ bias,
                                              const float* __restrict__ res,
                                              float* __restrict__ Cm,
                                              int M, int N, int K) {
    __shared__ float As[16][64];
    __shared__ float Ws[16][64];
    int t = threadIdx.x;
    int tm = t & 15, tn = t >> 4;
    int m0 = blockIdx.x * 64, n0 = blockIdx.y * 64;
    int lrow = t >> 2;
    int lk = (t & 3) * 4;
    float acc[4][4] = {};
    for (int k0 = 0; k0 < K; k0 += 16) {
        float4 av = *(const float4*)&A[(size_t)(m0 + lrow) * K + k0 + lk];
        float4 wv = *(const float4*)&W[(size_t)(n0 + lrow) * K + k0 + lk];
        __syncthreads();
        As[lk + 0][lrow] = av.x; As[lk + 1][lrow] = av.y;
        As[lk + 2][lrow] = av.z; As[lk + 3][lrow] = av.w;
        Ws[lk + 0][lrow] = wv.x; Ws[lk + 1][lrow] = wv.y;
        Ws[lk + 2][lrow] = wv.z; Ws[lk + 3][lrow] = wv.w;
        __syncthreads();
#pragma unroll
        for (int k = 0; k < 16; ++k) {
            float4 a = *(const float4*)&As[k][tm * 4];
            float4 b = *(const float4*)&Ws[k][tn * 4];
            acc[0][0] += a.x * b.x; acc[0][1] += a.x * b.y; acc[0][2] += a.x * b.z; acc[0][3] += a.x * b.w;
            acc[1][0] += a.y * b.x; acc[1][1] += a.y * b.y; acc[1][2] += a.y * b.z; acc[1][3] += a.y * b.w;
            acc[2][0] += a.z * b.x; acc[2][1] += a.z * b.y; acc[2][2] += a.z * b.z; acc[2][3] += a.z * b.w;
            acc[3][0] += a.w * b.x; acc[3][1] += a.w * b.y; acc[3][2] += a.w * b.z; acc[3][3] += a.w * b.w;
        }
    }
    float4 bv = make_float4(0.f, 0.f, 0.f, 0.f);
    if (EPI >= 1) bv = *(const float4*)&bias[n0 + tn * 4];
#pragma unroll
    for (int i = 0; i < 4; ++i) {
        int r = m0 + tm * 4 + i;
        float4 v;
        v.x = acc[i][0] + bv.x; v.y = acc[i][1] + bv.y;
        v.z = acc[i][2] + bv.z; v.w = acc[i][3] + bv.w;
        if (EPI == 2) {
            v.x = gelu_f(v.x); v.y = gelu_f(v.y); v.z = gelu_f(v.z); v.w = gelu_f(v.w);
        }
        if (EPI == 3) {
            float4 rv = *(const float4*)&res[(size_t)r * N + n0 + tn * 4];
            v.x += rv.x; v.y += rv.y; v.z += rv.z; v.w += rv.w;
        }
        *(float4*)&Cm[(size_t)r * N + n0 + tn * 4] = v;
    }
}

// ---------------- split-K fp32 GEMM: P[kp] = A[:, kp-slice] @ W[:, kp-slice]^T ----------------
__global__ __launch_bounds__(256) void gemm_splitk_k(const float* __restrict__ A,
                                                     const float* __restrict__ W,
                                                     float* __restrict__ P,
                                                     int M, int N, int K, int KS) {
    __shared__ float As[16][64];
    __shared__ float Ws[16][64];
    int t = threadIdx.x;
    int tm = t & 15, tn = t >> 4;
    int m0 = blockIdx.x * 64, n0 = blockIdx.y * 64;
    int kbeg = blockIdx.z * KS, kend = kbeg + KS;
    int lrow = t >> 2;
    int lk = (t & 3) * 4;
    float acc[4][4] = {};
    for (int k0 = kbeg; k0 < kend; k0 += 16) {
        float4 av = *(const float4*)&A[(size_t)(m0 + lrow) * K + k0 + lk];
        float4 wv = *(const float4*)&W[(size_t)(n0 + lrow) * K + k0 + lk];
        __syncthreads();
        As[lk + 0][lrow] = av.x; As[lk + 1][lrow] = av.y;
        As[lk + 2][lrow] = av.z; As[lk + 3][lrow] = av.w;
        Ws[lk + 0][lrow] = wv.x; Ws[lk + 1][lrow] = wv.y;
        Ws[lk + 2][lrow] = wv.z; Ws[lk + 3][lrow] = wv.w;
        __syncthreads();
#pragma unroll
        for (int k = 0; k < 16; ++k) {
            float4 a = *(const float4*)&As[k][tm * 4];
            float4 b = *(const float4*)&Ws[k][tn * 4];
            acc[0][0] += a.x * b.x; acc[0][1] += a.x * b.y; acc[0][2] += a.x * b.z; acc[0][3] += a.x * b.w;
            acc[1][0] += a.y * b.x; acc[1][1] += a.y * b.y; acc[1][2] += a.y * b.z; acc[1][3] += a.y * b.w;
            acc[2][0] += a.z * b.x; acc[2][1] += a.z * b.y; acc[2][2] += a.z * b.z; acc[2][3] += a.z * b.w;
            acc[3][0] += a.w * b.x; acc[3][1] += a.w * b.y; acc[3][2] += a.w * b.z; acc[3][3] += a.w * b.w;
        }
    }
    float* Pb = P + (size_t)blockIdx.z * M * N;
#pragma unroll
    for (int i = 0; i < 4; ++i) {
        int r = m0 + tm * 4 + i;
        float4 v = make_float4(acc[i][0], acc[i][1], acc[i][2], acc[i][3]);
        *(float4*)&Pb[(size_t)r * N + n0 + tn * 4] = v;
    }
}

// ---------------- local patch attention (R=256 patches, 8 heads, 32 tokens, HD=16) ----------------
__global__ __launch_bounds__(256) void local_attn_k(const float* __restrict__ qkv,
                                                    float* __restrict__ ob) {
    __shared__ float ks[NHD][32][HDIM];
    __shared__ float vs[NHD][32][HDIM];
    int m = threadIdx.x, h = threadIdx.y, r = blockIdx.x;
    int zd = r >> 6, zh = (r >> 3) & 7, zw = r & 7;
    int pd = m >> 4, ph = (m >> 2) & 3, pw = m & 3;
    int n = (zd * 2 + pd) * 1024 + (zh * 4 + ph) * 32 + (zw * 4 + pw);
    const float* base = qkv + (size_t)n * 384 + h * HDIM;
    float q[16];
#pragma unroll
    for (int i = 0; i < 4; ++i) {
        float4 qv = *(const float4*)(base + i * 4);
        q[i * 4 + 0] = qv.x; q[i * 4 + 1] = qv.y; q[i * 4 + 2] = qv.z; q[i * 4 + 3] = qv.w;
        *(float4*)&ks[h][m][i * 4] = *(const float4*)(base + 128 + i * 4);
        *(float4*)&vs[h][m][i * 4] = *(const float4*)(base + 256 + i * 4);
    }
    __syncthreads();
    float s[32];
    float mx = -1e30f;
#pragma unroll
    for (int j = 0; j < 32; ++j) {
        float d = 0.f;
#pragma unroll
        for (int dd = 0; dd < 16; ++dd) d += q[dd] * ks[h][j][dd];
        s[j] = d * QK_SCALE;
        mx = fmaxf(mx, s[j]);
    }
    float sum = 0.f;
#pragma unroll
    for (int j = 0; j < 32; ++j) { s[j] = __expf(s[j] - mx); sum += s[j]; }
    float inv = 1.0f / sum;
    float oo[16] = {};
#pragma unroll
    for (int j = 0; j < 32; ++j) {
        float p = s[j] * inv;
#pragma unroll
        for (int dd = 0; dd < 16; ++dd) oo[dd] += p * vs[h][j][dd];
    }
    // torch-faithful quirk: o (NH,Npl,HD) -> swap(-1,-2) -> reshape (Npl, C)
#pragma unroll
    for (int dd = 0; dd < 16; ++dd) {
        int n2 = h * 4 + (dd >> 2);
        int c2 = (dd & 3) * 32 + m;
        int pd2 = n2 >> 4, ph2 = (n2 >> 2) & 3, pw2 = n2 & 3;
        int nn = (zd * 2 + pd2) * 1024 + (zh * 4 + ph2) * 32 + (zw * 4 + pw2);
        ob[(size_t)nn * C_DIM + c2] = oo[dd];
    }
}

// ---------------- gather reduced K/V conv inputs: kg/vg (Nr=1024, 1024) ----------------
__global__ __launch_bounds__(256) void gather_k(const float* __restrict__ qkv,
                                                float* __restrict__ kg, float* __restrict__ vg) {
    int idx = blockIdx.x * 256 + threadIdx.x;
    int nr = idx >> 10, qq = idx & 1023;
    int ci = qq >> 3, off = qq & 7;
    int od = off >> 2, oh = (off >> 1) & 1, ow = off & 1;
    int d2 = nr >> 8, h2 = (nr >> 4) & 15, w2 = nr & 15;
    int n = (2 * d2 + od) * 1024 + (2 * h2 + oh) * 32 + (2 * w2 + ow);
    kg[idx] = qkv[(size_t)n * 384 + 128 + ci];
    vg[idx] = qkv[(size_t)n * 384 + 256 + ci];
}

// ---------------- sum 8 split-K partials + per-head LN over HD=16 ----------------
__global__ __launch_bounds__(256) void ln_head_sum_k(const float* __restrict__ part,
                                                     const float* __restrict__ g, const float* __restrict__ b,
                                                     float* __restrict__ out) {
    int idx = blockIdx.x * 256 + threadIdx.x; // 8192 = 1024*8
    int nr = idx >> 3, h = idx & 7;
    size_t base = (size_t)nr * C_DIM + h * HDIM;
    float v[16];
#pragma unroll
    for (int i = 0; i < 16; ++i) v[i] = 0.f;
#pragma unroll
    for (int p = 0; p < 8; ++p) {
        const float* pp = part + (size_t)p * (NR * C_DIM) + base;
#pragma unroll
        for (int d4 = 0; d4 < 4; ++d4) {
            float4 t = *(const float4*)(pp + d4 * 4);
            v[d4 * 4 + 0] += t.x; v[d4 * 4 + 1] += t.y;
            v[d4 * 4 + 2] += t.z; v[d4 * 4 + 3] += t.w;
        }
    }
    float s = 0.f;
#pragma unroll
    for (int i = 0; i < 16; ++i) s += v[i];
    float m = s * (1.0f / 16.0f);
    float sq = 0.f;
#pragma unroll
    for (int i = 0; i < 16; ++i) { float d = v[i] - m; sq += d * d; }
    float rs = rsqrtf(sq * (1.0f / 16.0f) + EPSV);
    float* op = out + base;
#pragma unroll
    for (int i = 0; i < 16; ++i) op[i] = (v[i] - m) * rs * g[i] + b[i];
}

// ---------------- global attention, register-tiled flash ----------------
// grid (256, 8); block 256. 32 queries/block, 8 groups of 32 lanes, 4 queries/thread.
#define GQ_TQ 4
__global__ __launch_bounds__(256) void gattn_k(const float* __restrict__ qkv,
                                               const float* __restrict__ kr, const float* __restrict__ vr,
                                               float* __restrict__ ob) {
    __shared__ float ks[64][20];   // 80B rows: 4-way max bank aliasing
    __shared__ float vs[64][20];
    __shared__ float qs[32][16];
    int t = threadIdx.x;
    int h = blockIdx.y;
    int g = t >> 5;      // query group 0..7 (contiguous 32 lanes = half wave)
    int i = t & 31;      // key slot within group
    int qbase = blockIdx.x * 32;

    if (t < 128) {
        int qq = t >> 2, d4 = t & 3;
        *(float4*)&qs[qq][d4 * 4] =
            *(const float4*)(qkv + (size_t)(qbase + qq) * 384 + h * HDIM + d4 * 4);
    }
    __syncthreads();

    float q[GQ_TQ][16];
#pragma unroll
    for (int a = 0; a < GQ_TQ; ++a)
#pragma unroll
        for (int d4 = 0; d4 < 4; ++d4) {
            float4 v = *(const float4*)&qs[g * GQ_TQ + a][d4 * 4];
            q[a][d4 * 4 + 0] = v.x * QK_SCALE; q[a][d4 * 4 + 1] = v.y * QK_SCALE;
            q[a][d4 * 4 + 2] = v.z * QK_SCALE; q[a][d4 * 4 + 3] = v.w * QK_SCALE;
        }

    float mx[GQ_TQ], sm[GQ_TQ], o[GQ_TQ][16];
#pragma unroll
    for (int a = 0; a < GQ_TQ; ++a) {
        mx[a] = -1e30f; sm[a] = 0.f;
#pragma unroll
        for (int d = 0; d < 16; ++d) o[a][d] = 0.f;
    }

    for (int c0 = 0; c0 < NR; c0 += 64) {
        __syncthreads();
        {
            int r = t >> 2, d4 = t & 3;
            *(float4*)&ks[r][d4 * 4] = *(const float4*)(kr + (size_t)(c0 + r) * C_DIM + h * HDIM + d4 * 4);
            *(float4*)&vs[r][d4 * 4] = *(const float4*)(vr + (size_t)(c0 + r) * C_DIM + h * HDIM + d4 * 4);
        }
        __syncthreads();

        float kA[16], kB[16];
#pragma unroll
        for (int d4 = 0; d4 < 4; ++d4) {
            float4 va = *(const float4*)&ks[i][d4 * 4];
            kA[d4 * 4 + 0] = va.x; kA[d4 * 4 + 1] = va.y; kA[d4 * 4 + 2] = va.z; kA[d4 * 4 + 3] = va.w;
            float4 vb = *(const float4*)&ks[i + 32][d4 * 4];
            kB[d4 * 4 + 0] = vb.x; kB[d4 * 4 + 1] = vb.y; kB[d4 * 4 + 2] = vb.z; kB[d4 * 4 + 3] = vb.w;
        }
        float s0[GQ_TQ], s1[GQ_TQ];
#pragma unroll
        for (int a = 0; a < GQ_TQ; ++a) {
            float d0 = 0.f, d1 = 0.f;
#pragma unroll
            for (int d = 0; d < 16; ++d) { d0 += q[a][d] * kA[d]; d1 += q[a][d] * kB[d]; }
            s0[a] = d0; s1[a] = d1;
        }
        float p0[GQ_TQ], p1[GQ_TQ];
#pragma unroll
        for (int a = 0; a < GQ_TQ; ++a) {
            float nm = fmaxf(mx[a], fmaxf(s0[a], s1[a]));
            if (nm > mx[a]) {
                float corr = __expf(mx[a] - nm);
                sm[a] *= corr;
#pragma unroll
                for (int d = 0; d < 16; ++d) o[a][d] *= corr;
                mx[a] = nm;
            }
            p0[a] = __expf(s0[a] - mx[a]);
            p1[a] = __expf(s1[a] - mx[a]);
            sm[a] += p0[a] + p1[a];
        }
        float vA[16], vB[16];
#pragma unroll
        for (int d4 = 0; d4 < 4; ++d4) {
            float4 va = *(const float4*)&vs[i][d4 * 4];
            vA[d4 * 4 + 0] = va.x; vA[d4 * 4 + 1] = va.y; vA[d4 * 4 + 2] = va.z; vA[d4 * 4 + 3] = va.w;
            float4 vb = *(const float4*)&vs[i + 32][d4 * 4];
            vB[d4 * 4 + 0] = vb.x; vB[d4 * 4 + 1] = vb.y; vB[d4 * 4 + 2] = vb.z; vB[d4 * 4 + 3] = vb.w;
        }
#pragma unroll
        for (int a = 0; a < GQ_TQ; ++a)
#pragma unroll
            for (int d = 0; d < 16; ++d) o[a][d] += p0[a] * vA[d] + p1[a] * vB[d];
    }

    // merge across the 32 lanes of the group (xor offsets stay within half-wave)
#pragma unroll
    for (int a = 0; a < GQ_TQ; ++a) {
        float m = mx[a];
#pragma unroll
        for (int off = 16; off >= 1; off >>= 1) m = fmaxf(m, __shfl_xor(m, off));
        float corr = __expf(mx[a] - m);
        float s2 = sm[a] * corr;
#pragma unroll
        for (int off = 16; off >= 1; off >>= 1) s2 += __shfl_xor(s2, off);
        float inv = 1.0f / s2;
#pragma unroll
        for (int d = 0; d < 16; ++d) {
            float val = o[a][d] * corr;
#pragma unroll
            for (int off = 16; off >= 1; off >>= 1) val += __shfl_xor(val, off);
            o[a][d] = val * inv;
        }
    }
    if (i == 0) {
        float* dst = ob + (size_t)(qbase + g * GQ_TQ) * C_DIM + h * HDIM;
#pragma unroll
        for (int a = 0; a < GQ_TQ; ++a)
#pragma unroll
            for (int d4 = 0; d4 < 4; ++d4) {
                float4 v = make_float4(o[a][d4 * 4 + 0], o[a][d4 * 4 + 1],
                                       o[a][d4 * 4 + 2], o[a][d4 * 4 + 3]);
                *(float4*)(dst + (size_t)a * C_DIM + d4 * 4) = v;
            }
    }
}

// ---------------- final gate: out(C,N) = x * sigmoid(loc + glo) ----------------
__global__ __launch_bounds__(256) void gate_k(const float* __restrict__ x,
                                              const float* __restrict__ lf, const float* __restrict__ gf,
                                              float* __restrict__ out) {
    __shared__ float tile[32][33];
    int n0 = blockIdx.x * 32, c0 = blockIdx.y * 32;
    int tx = threadIdx.x, ty = threadIdx.y;
#pragma unroll
    for (int k = 0; k < 4; ++k) {
        int n = n0 + ty + k * 8, c = c0 + tx;
        tile[ty + k * 8][tx] = lf[(size_t)n * C_DIM + c] + gf[(size_t)n * C_DIM + c];
    }
    __syncthreads();
#pragma unroll
    for (int k = 0; k < 4; ++k) {
        int c = c0 + ty + k * 8, n = n0 + tx;
        float z = tile[tx][ty + k * 8];
        float sg = 1.0f / (1.0f + __expf(-z));
        out[(size_t)c * N_TOK + n] = x[(size_t)c * N_TOK + n] * sg;
    }
}

extern "C" void kernel_launch(void* const* d_in, const int* in_sizes, int n_in,
                              void* d_out, int out_size, void* d_ws, size_t ws_size,
                              hipStream_t stream) {
    const float* x        = (const float*)d_in[0];
    const float* l_n1_g   = (const float*)d_in[1];
    const float* l_n1_b   = (const float*)d_in[2];
    const float* l_qkv_w  = (const float*)d_in[3];
    const float* l_proj_w = (const float*)d_in[4];
    const float* l_proj_b = (const float*)d_in[5];
    const float* l_n2_g   = (const float*)d_in[6];
    const float* l_n2_b   = (const float*)d_in[7];
    const float* l_fc1_w  = (const float*)d_in[8];
    const float* l_fc1_b  = (const float*)d_in[9];
    const float* l_fc2_w  = (const float*)d_in[10];
    const float* l_fc2_b  = (const float*)d_in[11];
    const float* g_n1_g   = (const float*)d_in[12];
    const float* g_n1_b   = (const float*)d_in[13];
    const float* g_qkv_w  = (const float*)d_in[14];
    const float* g_proj_w = (const float*)d_in[15];
    const float* g_proj_b = (const float*)d_in[16];
    const float* g_n2_g   = (const float*)d_in[17];
    const float* g_n2_b   = (const float*)d_in[18];
    const float* g_fc1_w  = (const float*)d_in[19];
    const float* g_fc1_b  = (const float*)d_in[20];
    const float* g_fc2_w  = (const float*)d_in[21];
    const float* g_fc2_b  = (const float*)d_in[22];
    const float* g_ke_w   = (const float*)d_in[23];
    const float* g_ve_w   = (const float*)d_in[24];
    const float* g_nk_g   = (const float*)d_in[25];
    const float* g_nk_b   = (const float*)d_in[26];
    const float* g_nv_g   = (const float*)d_in[27];
    const float* g_nv_b   = (const float*)d_in[28];
    float* out = (float*)d_out;

    float* ws = (float*)d_ws;
    float* xt     = ws;               // 1048576
    float* locfin = ws + 1048576;     // 1048576
    float* glofin = ws + 2097152;     // 1048576
    float* yA     = ws + 3145728;     // 1048576
    float* qkvb   = ws + 4194304;     // 3145728
    float* obuf   = ws + 7340032;     // 1048576
    float* t1     = ws + 8388608;     // 1048576
    float* t2     = ws + 9437184;     // 1048576
    float* h1     = ws + 10485760;    // 4194304
    float* kg     = ws + 14680064;    // 1048576
    float* vg     = ws + 15728640;    // 1048576
    float* krb    = ws + 16777216;    // 131072
    float* vrb    = ws + 16908288;    // 131072
    float* yG     = ws + 17039360;    // 1048576 (second LN output)
    // split-K partial buffers: reuse h1 (idle between local-MLP and global-MLP)
    float* kpart  = h1;               // 8 * 131072 = 1048576
    float* vpart  = h1 + 1048576;     // 8 * 131072 = 1048576

    // ---- shared preamble ----
    transpose_k<<<dim3(256, 4), dim3(32, 8), 0, stream>>>(x, xt);
    ln_token_k<<<2048, 256, 0, stream>>>(xt, l_n1_g, l_n1_b, yA, g_n1_g, g_n1_b, yG);

    // ---- local branch ----
    gemm_k<0><<<dim3(128, 6), 256, 0, stream>>>(yA, l_qkv_w, nullptr, nullptr, qkvb, N_TOK, 384, 128);
    local_attn_k<<<256, dim3(32, 8), 0, stream>>>(qkvb, obuf);
    gemm_k<3><<<dim3(128, 2), 256, 0, stream>>>(obuf, l_proj_w, l_proj_b, xt, t1, N_TOK, 128, 128);
    ln_token_k<<<2048, 256, 0, stream>>>(t1, l_n2_g, l_n2_b, t2, nullptr, nullptr, nullptr);
    gemm_k<2><<<dim3(128, 8), 256, 0, stream>>>(t2, l_fc1_w, l_fc1_b, nullptr, h1, N_TOK, 512, 128);
    gemm_k<3><<<dim3(128, 2), 256, 0, stream>>>(h1, l_fc2_w, l_fc2_b, t1, locfin, N_TOK, 128, 512);

    // ---- global branch ----
    gemm_k<0><<<dim3(128, 6), 256, 0, stream>>>(yG, g_qkv_w, nullptr, nullptr, qkvb, N_TOK, 384, 128);
    gather_k<<<4096, 256, 0, stream>>>(qkvb, kg, vg);
    gemm_splitk_k<<<dim3(16, 2, 8), 256, 0, stream>>>(kg, g_ke_w, kpart, NR, 128, 1024, 128);
    gemm_splitk_k<<<dim3(16, 2, 8), 256, 0, stream>>>(vg, g_ve_w, vpart, NR, 128, 1024, 128);
    ln_head_sum_k<<<32, 256, 0, stream>>>(kpart, g_nk_g, g_nk_b, krb);
    ln_head_sum_k<<<32, 256, 0, stream>>>(vpart, g_nv_g, g_nv_b, vrb);
    gattn_k<<<dim3(256, 8), 256, 0, stream>>>(qkvb, krb, vrb, obuf);
    gemm_k<3><<<dim3(128, 2), 256, 0, stream>>>(obuf, g_proj_w, g_proj_b, xt, t1, N_TOK, 128, 128);
    ln_token_k<<<2048, 256, 0, stream>>>(t1, g_n2_g, g_n2_b, t2, nullptr, nullptr, nullptr);
    gemm_k<2><<<dim3(128, 8), 256, 0, stream>>>(t2, g_fc1_w, g_fc1_b, nullptr, h1, N_TOK, 512, 128);
    gemm_k<3><<<dim3(128, 2), 256, 0, stream>>>(h1, g_fc2_w, g_fc2_b, t1, glofin, N_TOK, 128, 512);

    // ---- gate ----
    gate_k<<<dim3(256, 4), dim3(32, 8), 0, stream>>>(x, locfin, glofin, out);
}

// Round 3
// 324.299 us; speedup vs baseline: 1.7368x; 1.1286x over previous
//
#include <hip/hip_runtime.h>
#include <math.h>

#define N_TOK 8192
#define C_DIM 128
#define NHD   8
#define HDIM  16
#define NR    1024
#define EPSV  1e-5f
#define QK_SCALE 0.25f

typedef __attribute__((ext_vector_type(8))) short short8;
typedef __attribute__((ext_vector_type(4))) float f32x4;

__device__ __forceinline__ float gelu_f(float v) {
    return 0.5f * v * (1.0f + erff(v * 0.70710678118654752f));
}
__device__ __forceinline__ float uaf(unsigned int u) {
    union { unsigned int u; float f; } x; x.u = u; return x.f;
}
__device__ __forceinline__ short f2b(float v) {
    union { float f; unsigned int u; } x; x.f = v;
    unsigned int r = x.u + 0x7fffu + ((x.u >> 16) & 1u);
    return (short)(r >> 16);
}
// load 16 bf16 (32B, 16B-aligned) -> 16 floats
__device__ __forceinline__ void ld16bf(const short* p, float* d) {
    uint4 a = *(const uint4*)p;
    uint4 b = *(const uint4*)(p + 8);
    d[0]  = uaf(a.x << 16); d[1]  = uaf(a.x & 0xffff0000u);
    d[2]  = uaf(a.y << 16); d[3]  = uaf(a.y & 0xffff0000u);
    d[4]  = uaf(a.z << 16); d[5]  = uaf(a.z & 0xffff0000u);
    d[6]  = uaf(a.w << 16); d[7]  = uaf(a.w & 0xffff0000u);
    d[8]  = uaf(b.x << 16); d[9]  = uaf(b.x & 0xffff0000u);
    d[10] = uaf(b.y << 16); d[11] = uaf(b.y & 0xffff0000u);
    d[12] = uaf(b.z << 16); d[13] = uaf(b.z & 0xffff0000u);
    d[14] = uaf(b.w << 16); d[15] = uaf(b.w & 0xffff0000u);
}

// ---------------- weight fp32 -> bf16 conversion (all 10 weights, one launch) --------
struct CvtDesc { const float* src; short* dst; int n; int pad; };
struct CvtArgs { CvtDesc d[10]; };
__global__ __launch_bounds__(256) void cvtw_k(CvtArgs a) {
    CvtDesc dd = a.d[blockIdx.y];
    for (int i = blockIdx.x * 256 + threadIdx.x; i < dd.n; i += gridDim.x * 256)
        dd.dst[i] = f2b(dd.src[i]);
}

// ---------------- transpose x (C,N) -> xt (N,C) f32 ----------------
__global__ __launch_bounds__(256) void transpose_k(const float* __restrict__ x,
                                                   float* __restrict__ xt) {
    __shared__ float tile[32][33];
    int n0 = blockIdx.x * 32, c0 = blockIdx.y * 32;
    int tx = threadIdx.x, ty = threadIdx.y;
#pragma unroll
    for (int k = 0; k < 4; ++k)
        tile[ty + k * 8][tx] = x[(size_t)(c0 + ty + k * 8) * N_TOK + n0 + tx];
    __syncthreads();
#pragma unroll
    for (int k = 0; k < 4; ++k)
        xt[(size_t)(n0 + ty + k * 8) * C_DIM + c0 + tx] = tile[tx][ty + k * 8];
}

// ---------------- token LayerNorm over C=128, fp32 in, bf16 out (up to 2 sets) -------
__global__ __launch_bounds__(256) void ln_token_k(const float* __restrict__ in,
                                                  const float* __restrict__ g1, const float* __restrict__ b1,
                                                  short* __restrict__ o1,
                                                  const float* __restrict__ g2, const float* __restrict__ b2,
                                                  short* __restrict__ o2) {
    int lane = threadIdx.x & 63;
    int n = blockIdx.x * 4 + (threadIdx.x >> 6);
    float v0 = in[(size_t)n * C_DIM + lane];
    float v1 = in[(size_t)n * C_DIM + 64 + lane];
    float s = v0 + v1, sq = v0 * v0 + v1 * v1;
#pragma unroll
    for (int off = 32; off >= 1; off >>= 1) {
        s += __shfl_xor(s, off);
        sq += __shfl_xor(sq, off);
    }
    float m = s * (1.0f / 128.0f);
    float var = sq * (1.0f / 128.0f) - m * m;
    float rs = rsqrtf(var + EPSV);
    float h0 = (v0 - m) * rs, h1 = (v1 - m) * rs;
    o1[(size_t)n * C_DIM + lane]      = f2b(h0 * g1[lane] + b1[lane]);
    o1[(size_t)n * C_DIM + 64 + lane] = f2b(h1 * g1[lane + 64] + b1[lane + 64]);
    if (o2) {
        o2[(size_t)n * C_DIM + lane]      = f2b(h0 * g2[lane] + b2[lane]);
        o2[(size_t)n * C_DIM + 64 + lane] = f2b(h1 * g2[lane + 64] + b2[lane + 64]);
    }
}

// ---------------- bf16 MFMA GEMM: C = A(MxK) @ W(NxK)^T ----------------
// 128x128 tile, BK=64, 256 threads (4 waves, 2x2), mfma_f32_16x16x32_bf16.
// EPI: 0 -> bf16 out (no bias)
//      1 -> f32 out = acc + bias + res
//      2 -> bf16 out = gelu(acc + bias)
//      3 -> f32 split-K partial: out + blockIdx.z*M*N
template <int EPI>
__global__ __launch_bounds__(256) void mgemm_k(const short* __restrict__ A,
                                               const short* __restrict__ W,
                                               const float* __restrict__ bias,
                                               const float* __restrict__ res,
                                               void* __restrict__ outp,
                                               int M, int N, int K, int kslice) {
    __shared__ short As[128 * 64];
    __shared__ short Bs[128 * 64];
    int t = threadIdx.x;
    int w = t >> 6, l = t & 63;
    int m0 = blockIdx.x * 128, n0 = blockIdx.y * 128;
    int wm = (w >> 1) * 64, wn = (w & 1) * 64;
    int kbeg = (EPI == 3) ? blockIdx.z * kslice : 0;
    int kend = kbeg + kslice;

    f32x4 acc[4][4];
#pragma unroll
    for (int a = 0; a < 4; ++a)
#pragma unroll
        for (int b = 0; b < 4; ++b) acc[a][b] = f32x4{0.f, 0.f, 0.f, 0.f};

    for (int k0 = kbeg; k0 < kend; k0 += 64) {
        __syncthreads();
#pragma unroll
        for (int c = 0; c < 4; ++c) {
            int chunk = c * 256 + t;       // 0..1023
            int row = chunk >> 3;          // 0..127
            int slot = chunk & 7;          // 16B slot within 128B row
            int ss = slot ^ (row & 7);     // XOR swizzle (T2)
            uint4 av = *(const uint4*)(A + (size_t)(m0 + row) * K + k0 + slot * 8);
            *(uint4*)(As + row * 64 + ss * 8) = av;
            uint4 wv = *(const uint4*)(W + (size_t)(n0 + row) * K + k0 + slot * 8);
            *(uint4*)(Bs + row * 64 + ss * 8) = wv;
        }
        __syncthreads();
#pragma unroll
        for (int kk = 0; kk < 2; ++kk) {
            short8 af[4], bf[4];
            int sl = kk * 4 + (l >> 4);
#pragma unroll
            for (int mf = 0; mf < 4; ++mf) {
                int row = wm + mf * 16 + (l & 15);
                af[mf] = *(const short8*)(As + row * 64 + (sl ^ (row & 7)) * 8);
            }
#pragma unroll
            for (int nf = 0; nf < 4; ++nf) {
                int row = wn + nf * 16 + (l & 15);
                bf[nf] = *(const short8*)(Bs + row * 64 + (sl ^ (row & 7)) * 8);
            }
#pragma unroll
            for (int mf = 0; mf < 4; ++mf)
#pragma unroll
                for (int nf = 0; nf < 4; ++nf)
                    acc[mf][nf] = __builtin_amdgcn_mfma_f32_16x16x32_bf16(
                        af[mf], bf[nf], acc[mf][nf], 0, 0, 0);
        }
    }

    // C/D layout (verified m89/m91): col = lane&15, row = (lane>>4)*4 + reg
#pragma unroll
    for (int mf = 0; mf < 4; ++mf) {
#pragma unroll
        for (int nf = 0; nf < 4; ++nf) {
            int col = n0 + wn + nf * 16 + (l & 15);
#pragma unroll
            for (int j = 0; j < 4; ++j) {
                int row = m0 + wm + mf * 16 + (l >> 4) * 4 + j;
                float v = acc[mf][nf][j];
                if (EPI == 0) {
                    ((short*)outp)[(size_t)row * N + col] = f2b(v);
                } else if (EPI == 1) {
                    v += bias[col] + res[(size_t)row * N + col];
                    ((float*)outp)[(size_t)row * N + col] = v;
                } else if (EPI == 2) {
                    v = gelu_f(v + bias[col]);
                    ((short*)outp)[(size_t)row * N + col] = f2b(v);
                } else {
                    ((float*)outp)[(size_t)blockIdx.z * M * N + (size_t)row * N + col] = v;
                }
            }
        }
    }
}

// ---------------- local patch attention, bf16 in/out ----------------
__global__ __launch_bounds__(256) void local_attn_k(const short* __restrict__ qkv,
                                                    short* __restrict__ ob) {
    __shared__ float ks[NHD][32][HDIM];
    __shared__ float vs[NHD][32][HDIM];
    int m = threadIdx.x, h = threadIdx.y, r = blockIdx.x;
    int zd = r >> 6, zh = (r >> 3) & 7, zw = r & 7;
    int pd = m >> 4, ph = (m >> 2) & 3, pw = m & 3;
    int n = (zd * 2 + pd) * 1024 + (zh * 4 + ph) * 32 + (zw * 4 + pw);
    const short* base = qkv + (size_t)n * 384 + h * HDIM;
    float q[16], kt[16], vt[16];
    ld16bf(base, q);
    ld16bf(base + 128, kt);
    ld16bf(base + 256, vt);
#pragma unroll
    for (int d = 0; d < 16; ++d) { ks[h][m][d] = kt[d]; vs[h][m][d] = vt[d]; }
    __syncthreads();
    float s[32];
#pragma unroll
    for (int j = 0; j < 32; ++j) {
        float d = 0.f;
#pragma unroll
        for (int dd = 0; dd < 16; ++dd) d += q[dd] * ks[h][j][dd];
        s[j] = __expf(d * QK_SCALE);   // scores bounded: no max subtraction needed
    }
    float sum = 0.f;
#pragma unroll
    for (int j = 0; j < 32; ++j) sum += s[j];
    float inv = 1.0f / sum;
    float oo[16] = {};
#pragma unroll
    for (int j = 0; j < 32; ++j) {
        float p = s[j] * inv;
#pragma unroll
        for (int dd = 0; dd < 16; ++dd) oo[dd] += p * vs[h][j][dd];
    }
    // torch-faithful quirk: o (NH,Npl,HD) -> swap(-1,-2) -> reshape (Npl, C)
#pragma unroll
    for (int dd = 0; dd < 16; ++dd) {
        int n2 = h * 4 + (dd >> 2);
        int c2 = (dd & 3) * 32 + m;
        int pd2 = n2 >> 4, ph2 = (n2 >> 2) & 3, pw2 = n2 & 3;
        int nn = (zd * 2 + pd2) * 1024 + (zh * 4 + ph2) * 32 + (zw * 4 + pw2);
        ob[(size_t)nn * C_DIM + c2] = f2b(oo[dd]);
    }
}

// ---------------- gather reduced K/V conv inputs (bf16 passthrough) ----------------
__global__ __launch_bounds__(256) void gather_k(const short* __restrict__ qkv,
                                                short* __restrict__ kg, short* __restrict__ vg) {
    int idx = blockIdx.x * 256 + threadIdx.x;
    int nr = idx >> 10, qq = idx & 1023;
    int ci = qq >> 3, off = qq & 7;
    int od = off >> 2, oh = (off >> 1) & 1, ow = off & 1;
    int d2 = nr >> 8, h2 = (nr >> 4) & 15, w2 = nr & 15;
    int n = (2 * d2 + od) * 1024 + (2 * h2 + oh) * 32 + (2 * w2 + ow);
    kg[idx] = qkv[(size_t)n * 384 + 128 + ci];
    vg[idx] = qkv[(size_t)n * 384 + 256 + ci];
}

// ---------------- sum 4 split-K partials + per-head LN; out f32 [8][1024][16] --------
__global__ __launch_bounds__(256) void ln_head_sum_k(const float* __restrict__ part,
                                                     const float* __restrict__ g, const float* __restrict__ b,
                                                     float* __restrict__ out) {
    int idx = blockIdx.x * 256 + threadIdx.x; // 8192 = 1024*8
    int nr = idx >> 3, h = idx & 7;
    size_t base = (size_t)nr * C_DIM + h * HDIM;
    float v[16] = {};
#pragma unroll
    for (int p = 0; p < 4; ++p) {
        const float* pp = part + (size_t)p * (NR * C_DIM) + base;
#pragma unroll
        for (int d4 = 0; d4 < 4; ++d4) {
            float4 t = *(const float4*)(pp + d4 * 4);
            v[d4 * 4 + 0] += t.x; v[d4 * 4 + 1] += t.y;
            v[d4 * 4 + 2] += t.z; v[d4 * 4 + 3] += t.w;
        }
    }
    float s = 0.f;
#pragma unroll
    for (int i = 0; i < 16; ++i) s += v[i];
    float m = s * (1.0f / 16.0f);
    float sq = 0.f;
#pragma unroll
    for (int i = 0; i < 16; ++i) { float d = v[i] - m; sq += d * d; }
    float rs = rsqrtf(sq * (1.0f / 16.0f) + EPSV);
    float* op = out + (size_t)h * (NR * HDIM) + (size_t)nr * HDIM;
#pragma unroll
    for (int i = 0; i < 16; ++i) op[i] = (v[i] - m) * rs * g[i] + b[i];
}

// ---------------- global attention v3: no LDS, no barriers, streamed from L2 --------
// grid (256, 8); block 256. 8 groups of 32 lanes; 4 queries/group; keys striped x32.
__global__ __launch_bounds__(256) void gattn_k(const short* __restrict__ qkv,
                                               const float* __restrict__ kr,  // [8][1024][16]
                                               const float* __restrict__ vr,
                                               short* __restrict__ ob) {
    int t = threadIdx.x;
    int h = blockIdx.y;
    int g = t >> 5, i = t & 31;
    int q0 = blockIdx.x * 32 + g * 4;

    float q[4][16];
#pragma unroll
    for (int a = 0; a < 4; ++a) {
        ld16bf(qkv + (size_t)(q0 + a) * 384 + h * HDIM, q[a]);
#pragma unroll
        for (int d = 0; d < 16; ++d) q[a][d] *= QK_SCALE;
    }
    const float* kh = kr + (size_t)h * (NR * HDIM);
    const float* vh = vr + (size_t)h * (NR * HDIM);

    float sm[4] = {0.f, 0.f, 0.f, 0.f};
    float o[4][16] = {};
#pragma unroll 2
    for (int j = i; j < NR; j += 32) {
        float kv[16], vv[16];
#pragma unroll
        for (int d4 = 0; d4 < 4; ++d4)
            *(float4*)&kv[d4 * 4] = *(const float4*)(kh + j * HDIM + d4 * 4);
        float p[4];
#pragma unroll
        for (int a = 0; a < 4; ++a) {
            float s = 0.f;
#pragma unroll
            for (int d = 0; d < 16; ++d) s += q[a][d] * kv[d];
            p[a] = __expf(s);   // scores bounded: skip max tracking
            sm[a] += p[a];
        }
#pragma unroll
        for (int d4 = 0; d4 < 4; ++d4)
            *(float4*)&vv[d4 * 4] = *(const float4*)(vh + j * HDIM + d4 * 4);
#pragma unroll
        for (int a = 0; a < 4; ++a)
#pragma unroll
            for (int d = 0; d < 16; ++d) o[a][d] += p[a] * vv[d];
    }
    // butterfly reduce across the 32-lane group
#pragma unroll
    for (int a = 0; a < 4; ++a) {
#pragma unroll
        for (int off = 16; off >= 1; off >>= 1) sm[a] += __shfl_xor(sm[a], off);
#pragma unroll
        for (int d = 0; d < 16; ++d) {
            float v = o[a][d];
#pragma unroll
            for (int off = 16; off >= 1; off >>= 1) v += __shfl_xor(v, off);
            o[a][d] = v;
        }
    }
    if (i < 16) {
#pragma unroll
        for (int a = 0; a < 4; ++a)
            ob[(size_t)(q0 + a) * C_DIM + h * HDIM + i] = f2b(o[a][i] / sm[a]);
    }
}

// ---------------- final gate: out(C,N) = x * sigmoid(loc + glo) ----------------
__global__ __launch_bounds__(256) void gate_k(const float* __restrict__ x,
                                              const float* __restrict__ lf, const float* __restrict__ gf,
                                              float* __restrict__ out) {
    __shared__ float tile[32][33];
    int n0 = blockIdx.x * 32, c0 = blockIdx.y * 32;
    int tx = threadIdx.x, ty = threadIdx.y;
#pragma unroll
    for (int k = 0; k < 4; ++k) {
        int n = n0 + ty + k * 8, c = c0 + tx;
        tile[ty + k * 8][tx] = lf[(size_t)n * C_DIM + c] + gf[(size_t)n * C_DIM + c];
    }
    __syncthreads();
#pragma unroll
    for (int k = 0; k < 4; ++k) {
        int c = c0 + ty + k * 8, n = n0 + tx;
        float z = tile[tx][ty + k * 8];
        float sg = 1.0f / (1.0f + __expf(-z));
        out[(size_t)c * N_TOK + n] = x[(size_t)c * N_TOK + n] * sg;
    }
}

extern "C" void kernel_launch(void* const* d_in, const int* in_sizes, int n_in,
                              void* d_out, int out_size, void* d_ws, size_t ws_size,
                              hipStream_t stream) {
    const float* x        = (const float*)d_in[0];
    const float* l_n1_g   = (const float*)d_in[1];
    const float* l_n1_b   = (const float*)d_in[2];
    const float* l_qkv_w  = (const float*)d_in[3];
    const float* l_proj_w = (const float*)d_in[4];
    const float* l_proj_b = (const float*)d_in[5];
    const float* l_n2_g   = (const float*)d_in[6];
    const float* l_n2_b   = (const float*)d_in[7];
    const float* l_fc1_w  = (const float*)d_in[8];
    const float* l_fc1_b  = (const float*)d_in[9];
    const float* l_fc2_w  = (const float*)d_in[10];
    const float* l_fc2_b  = (const float*)d_in[11];
    const float* g_n1_g   = (const float*)d_in[12];
    const float* g_n1_b   = (const float*)d_in[13];
    const float* g_qkv_w  = (const float*)d_in[14];
    const float* g_proj_w = (const float*)d_in[15];
    const float* g_proj_b = (const float*)d_in[16];
    const float* g_n2_g   = (const float*)d_in[17];
    const float* g_n2_b   = (const float*)d_in[18];
    const float* g_fc1_w  = (const float*)d_in[19];
    const float* g_fc1_b  = (const float*)d_in[20];
    const float* g_fc2_w  = (const float*)d_in[21];
    const float* g_fc2_b  = (const float*)d_in[22];
    const float* g_ke_w   = (const float*)d_in[23];
    const float* g_ve_w   = (const float*)d_in[24];
    const float* g_nk_g   = (const float*)d_in[25];
    const float* g_nk_b   = (const float*)d_in[26];
    const float* g_nv_g   = (const float*)d_in[27];
    const float* g_nv_b   = (const float*)d_in[28];
    float* out = (float*)d_out;

    char* base = (char*)d_ws;
    float* xt     = (float*)(base);                        // 4 MB
    float* t1     = (float*)(base + (4ull  << 20));        // 4 MB
    float* locfin = (float*)(base + (8ull  << 20));        // 4 MB
    float* glofin = (float*)(base + (12ull << 20));        // 4 MB
    float* kpart  = (float*)(base + (16ull << 20));        // 2 MB (4x1024x128)
    float* vpart  = (float*)(base + (18ull << 20));        // 2 MB
    float* krb    = (float*)(base + (20ull << 20));        // 512 KB [8][1024][16]
    float* vrb    = (float*)(base + (21ull << 20));        // 512 KB
    short* qkvb   = (short*)(base + (22ull << 20));        // 6 MB  (8192x384)
    short* yA16   = (short*)(base + (28ull << 20));        // 2 MB
    short* yG16   = (short*)(base + (30ull << 20));        // 2 MB
    short* obuf16 = (short*)(base + (32ull << 20));        // 2 MB
    short* t2_16  = (short*)(base + (34ull << 20));        // 2 MB
    short* h1_16  = (short*)(base + (36ull << 20));        // 8 MB (8192x512)
    short* kg16   = (short*)(base + (44ull << 20));        // 2 MB
    short* vg16   = (short*)(base + (46ull << 20));        // 2 MB
    short* wts    = (short*)(base + (48ull << 20));        // ~1.3 MB

    // weight arena offsets (elements)
    const int L_QKV = 0,      L_PROJ = 49152, L_FC1 = 65536,  L_FC2 = 131072;
    const int G_QKV = 196608, G_PROJ = 245760, G_FC1 = 262144, G_FC2 = 327680;
    const int G_KE  = 393216, G_VE   = 524288;

    CvtArgs ca;
    ca.d[0] = {l_qkv_w,  wts + L_QKV,  49152, 0};
    ca.d[1] = {l_proj_w, wts + L_PROJ, 16384, 0};
    ca.d[2] = {l_fc1_w,  wts + L_FC1,  65536, 0};
    ca.d[3] = {l_fc2_w,  wts + L_FC2,  65536, 0};
    ca.d[4] = {g_qkv_w,  wts + G_QKV,  49152, 0};
    ca.d[5] = {g_proj_w, wts + G_PROJ, 16384, 0};
    ca.d[6] = {g_fc1_w,  wts + G_FC1,  65536, 0};
    ca.d[7] = {g_fc2_w,  wts + G_FC2,  65536, 0};
    ca.d[8] = {g_ke_w,   wts + G_KE,  131072, 0};
    ca.d[9] = {g_ve_w,   wts + G_VE,  131072, 0};

    // ---- preamble ----
    cvtw_k<<<dim3(32, 10), 256, 0, stream>>>(ca);
    transpose_k<<<dim3(256, 4), dim3(32, 8), 0, stream>>>(x, xt);
    ln_token_k<<<2048, 256, 0, stream>>>(xt, l_n1_g, l_n1_b, yA16, g_n1_g, g_n1_b, yG16);

    // ---- local branch ----
    mgemm_k<0><<<dim3(64, 3), 256, 0, stream>>>(yA16, wts + L_QKV, nullptr, nullptr, qkvb, N_TOK, 384, 128, 128);
    local_attn_k<<<256, dim3(32, 8), 0, stream>>>(qkvb, obuf16);
    mgemm_k<1><<<dim3(64, 1), 256, 0, stream>>>(obuf16, wts + L_PROJ, l_proj_b, xt, t1, N_TOK, 128, 128, 128);
    ln_token_k<<<2048, 256, 0, stream>>>(t1, l_n2_g, l_n2_b, t2_16, nullptr, nullptr, nullptr);
    mgemm_k<2><<<dim3(64, 4), 256, 0, stream>>>(t2_16, wts + L_FC1, l_fc1_b, nullptr, h1_16, N_TOK, 512, 128, 128);
    mgemm_k<1><<<dim3(64, 1), 256, 0, stream>>>(h1_16, wts + L_FC2, l_fc2_b, t1, locfin, N_TOK, 128, 512, 512);

    // ---- global branch ----
    mgemm_k<0><<<dim3(64, 3), 256, 0, stream>>>(yG16, wts + G_QKV, nullptr, nullptr, qkvb, N_TOK, 384, 128, 128);
    gather_k<<<4096, 256, 0, stream>>>(qkvb, kg16, vg16);
    mgemm_k<3><<<dim3(8, 1, 4), 256, 0, stream>>>(kg16, wts + G_KE, nullptr, nullptr, kpart, NR, 128, 1024, 256);
    mgemm_k<3><<<dim3(8, 1, 4), 256, 0, stream>>>(vg16, wts + G_VE, nullptr, nullptr, vpart, NR, 128, 1024, 256);
    ln_head_sum_k<<<32, 256, 0, stream>>>(kpart, g_nk_g, g_nk_b, krb);
    ln_head_sum_k<<<32, 256, 0, stream>>>(vpart, g_nv_g, g_nv_b, vrb);
    gattn_k<<<dim3(256, 8), 256, 0, stream>>>(qkvb, krb, vrb, obuf16);
    mgemm_k<1><<<dim3(64, 1), 256, 0, stream>>>(obuf16, wts + G_PROJ, g_proj_b, xt, t1, N_TOK, 128, 128, 128);
    ln_token_k<<<2048, 256, 0, stream>>>(t1, g_n2_g, g_n2_b, t2_16, nullptr, nullptr, nullptr);
    mgemm_k<2><<<dim3(64, 4), 256, 0, stream>>>(t2_16, wts + G_FC1, g_fc1_b, nullptr, h1_16, N_TOK, 512, 128, 128);
    mgemm_k<1><<<dim3(64, 1), 256, 0, stream>>>(h1_16, wts + G_FC2, g_fc2_b, t1, glofin, N_TOK, 128, 512, 512);

    // ---- gate ----
    gate_k<<<dim3(256, 4), dim3(32, 8), 0, stream>>>(x, locfin, glofin, out);
}